// Round 6
// baseline (54278.180 us; speedup 1.0000x reference)
//
#include <hip/hip_runtime.h>
#include <math.h>

#define T_STEPS 4096
#define EMB 1024
#define HID 2048
#define CAT 1040
#define TAG 16
#define NBLK 256
#define NTHR 1024

// output offsets (floats)
#define OUT_LOGP 0
#define OUT_PROB (T_STEPS * TAG)
#define OUT_PRED (2 * T_STEPS * TAG)

__device__ __forceinline__ float sigf(float x) { return 1.0f / (1.0f + expf(-x)); }

__device__ __forceinline__ float aload(const float* p) {
  return __hip_atomic_load(p, __ATOMIC_RELAXED, __HIP_MEMORY_SCOPE_AGENT);
}
__device__ __forceinline__ void astore(float* p, float v) {
  __hip_atomic_store(p, v, __ATOMIC_RELAXED, __HIP_MEMORY_SCOPE_AGENT);
}

// Fence-free grid barrier, PACKED flags (4B stride).
// Arrival: block b stores epoch to flags[b] (word-granular agent atomic ->
// coherent point). Poll: threads 0..255 poll flags[tid]; contiguous layout
// lets the per-wave coalescer merge 64 polls into 4 line requests (16x less
// fabric traffic than the 128B-strided R5 layout). No release/acquire ops ->
// no buffer_inv -> L2-resident weights/U/VT survive all 8192 barriers.
__device__ __forceinline__ void gbar(unsigned* __restrict__ flags, unsigned epoch) {
  const int tid = threadIdx.x;
  __syncthreads();
  if (tid == 0) {
    asm volatile("s_waitcnt vmcnt(0)" ::: "memory");  // drain wave-0 data stores
    __hip_atomic_store(flags + blockIdx.x, epoch,
                       __ATOMIC_RELAXED, __HIP_MEMORY_SCOPE_AGENT);
  }
  if (tid < NBLK) {
    const unsigned* f = flags + tid;
    while (__hip_atomic_load(f, __ATOMIC_RELAXED, __HIP_MEMORY_SCOPE_AGENT) < epoch)
      __builtin_amdgcn_s_sleep(1);
  }
  asm volatile("" ::: "memory");  // compiler-only: keep data loads after poll
  __syncthreads();
}

// ---- VT[p][i] = W_embed[i][1024+p]  (compact one-hot columns) ----
__global__ __launch_bounds__(256) void rnnss_vt_kernel(const float* __restrict__ We,
                                                       float* __restrict__ VT) {
  int n = blockIdx.x * 256 + threadIdx.x;      // 0..16383
  int p = n >> 10, i = n & 1023;
  VT[n] = We[(size_t)i * CAT + EMB + p];
}

// ---- U[t][i] = sum_k seq[t][k] * W_embed[i][k] + b_embed[i] ----
__global__ __launch_bounds__(256) void rnnss_uprep(const float* __restrict__ X,
                                                   const float* __restrict__ W,
                                                   const float* __restrict__ be,
                                                   float* __restrict__ U) {
  __shared__ __align__(16) float As[32][68];
  __shared__ __align__(16) float Bs[32][68];
  const int bm = blockIdx.x * 64;
  const int bn = blockIdx.y * 64;
  const int tid = threadIdx.x;
  const int tx = tid & 15, ty = tid >> 4;
  const int lr = tid >> 5, lc = tid & 31;
  float acc[4][4] = {};
  for (int k0 = 0; k0 < EMB; k0 += 32) {
#pragma unroll
    for (int p = 0; p < 8; ++p) {
      As[lc][lr + 8 * p] = X[(size_t)(bm + lr + 8 * p) * EMB + k0 + lc];
      Bs[lc][lr + 8 * p] = W[(size_t)(bn + lr + 8 * p) * CAT + k0 + lc];
    }
    __syncthreads();
#pragma unroll 8
    for (int k = 0; k < 32; ++k) {
      const float4 a = *(const float4*)&As[k][ty * 4];
      const float4 v = *(const float4*)&Bs[k][tx * 4];
      float am[4] = {a.x, a.y, a.z, a.w};
      float bv[4] = {v.x, v.y, v.z, v.w};
#pragma unroll
      for (int m = 0; m < 4; ++m)
#pragma unroll
        for (int n = 0; n < 4; ++n) acc[m][n] = fmaf(am[m], bv[n], acc[m][n]);
    }
    __syncthreads();
  }
#pragma unroll
  for (int m = 0; m < 4; ++m)
#pragma unroll
    for (int n = 0; n < 4; ++n)
      U[(size_t)(bm + ty * 4 + m) * EMB + bn + tx * 4 + n] =
          acc[m][n] + be[bn + tx * 4 + n];
}

// ---- persistent LSTM labeler: 256 blocks x 1024 threads ----
// FRESH=1: h/tpg buffers are t-indexed (never-reuse addresses). Producers
//   write via agent atomics (-> MALL, acked before flag); consumers use PLAIN
//   CACHED loads: a never-seen line cannot be stale in any cache, so the first
//   reader per XCD fills L2 and the other 31 blocks hit XCD-L2 (~32x fewer
//   coherent-point reads per broadcast).
// FRESH=0 (ws too small): single-slot buffers + relaxed agent atomic loads
//   (R5-proven semantics).
template <int FRESH>
__global__ __launch_bounds__(NTHR, 4) void rnnss_persist(
    const float* __restrict__ Wih, const float* __restrict__ Whh,
    const float* __restrict__ bih, const float* __restrict__ bhh,
    const float* __restrict__ Witm, const float* __restrict__ bitm,
    const float* __restrict__ Wtag, const float* __restrict__ btag,
    const float* __restrict__ U, const float* __restrict__ VT,
    float* __restrict__ hbase,  // FRESH: [T][2048] ; else [2048]
    float* __restrict__ tpgb,   // FRESH: [T][16][256] ; else [16][256]
    unsigned* __restrict__ flags,
    float* __restrict__ out) {
  __shared__ __align__(16) float sWi[32 * 1024];  // 128 KB: this block's W_ih rows
  __shared__ __align__(16) float se[EMB];
  __shared__ __align__(16) float sh[HID];
  __shared__ float sg[32];     // gate preacts for this block's 8 units
  __shared__ float wpart[16];  // per-wave partials (phase B)
  __shared__ float siv[4];     // interm values for this block's 4 rows
  __shared__ float stv[TAG];   // reduced tag scores
  __shared__ float sc[8];      // persistent cell state (block-owned units)

  const int tid = threadIdx.x;
  const int b = blockIdx.x;
  const int u0 = b * 8;                 // hidden units [u0, u0+8)
  if (tid < 8) sc[tid] = 0.0f;
  sh[tid] = 0.0f;                       // h_0 = 0 (phase A reads sh, never global)
  sh[tid + 1024] = 0.0f;

  // phase A row task: 32 gate rows x 32 lanes
  const int rt = tid >> 5;              // 0..31 : gsec*8 + j
  const int q = tid & 31;
  const int gsec = rt >> 3, j = rt & 7;
  const int grow = gsec * HID + u0 + j;
  const float bsum = bih[grow] + bhh[grow];
  const float4* __restrict__ wh = (const float4*)(Whh + (size_t)grow * HID);

  // phase B row task: 4 interm rows x 256 lanes
  const int brow = tid >> 8, bq = tid & 255;
  const float4* __restrict__ wm = (const float4*)(Witm + (size_t)(b * 4 + brow) * HID);
  float bitv = 0.0f;
  if (tid < 4) bitv = bitm[b * 4 + tid];
  float wt0 = 0, wt1 = 0, wt2 = 0, wt3 = 0;
  if (tid < TAG) {
    wt0 = Wtag[(size_t)tid * 1024 + b * 4 + 0];
    wt1 = Wtag[(size_t)tid * 1024 + b * 4 + 1];
    wt2 = Wtag[(size_t)tid * 1024 + b * 4 + 2];
    wt3 = Wtag[(size_t)tid * 1024 + b * 4 + 3];
  }
  float btw = 0.0f;
  if ((tid & 63) == 0) btw = btag[tid >> 6];

  // ---- prologue: W_ih slice -> LDS (coalesced float4) ----
  {
    const float4* WiF = (const float4*)Wih;
    float4* sWiF = (float4*)sWi;
#pragma unroll
    for (int n = 0; n < 8; ++n) {
      int idx = tid + 1024 * n;          // 0..8191 float4s
      int r = idx >> 8, c = idx & 255;
      int gr = (r >> 3) * HID + u0 + (r & 7);
      sWiF[idx] = WiF[(size_t)gr * 256 + c];
    }
  }

  // ---- prologue: W_hh + W_interm slices -> registers, PINNED ----
  float4 rwh[16], rwm[2];
#pragma unroll
  for (int it = 0; it < 16; ++it) rwh[it] = wh[q + 32 * it];
  rwm[0] = wm[bq];
  rwm[1] = wm[bq + 256];
#pragma unroll
  for (int it = 0; it < 16; ++it)
    asm volatile("" : "+v"(rwh[it].x), "+v"(rwh[it].y), "+v"(rwh[it].z), "+v"(rwh[it].w));
  asm volatile("" : "+v"(rwm[0].x), "+v"(rwm[0].y), "+v"(rwm[0].z), "+v"(rwm[0].w));
  asm volatile("" : "+v"(rwm[1].x), "+v"(rwm[1].y), "+v"(rwm[1].z), "+v"(rwm[1].w));

  const float4* sef = (const float4*)se;
  const float4* shf = (const float4*)sh;
  const float4* sWiF4 = (const float4*)sWi;

  int pred = 0;               // __START__
  float u_cur = U[tid];       // U[0] prefetched
  __syncthreads();            // sWi / sc / sh ready

  for (int t = 0; t < T_STEPS; ++t) {
    float* __restrict__ hrow = FRESH ? hbase + (size_t)t * HID : hbase;
    float* __restrict__ tpb  = FRESH ? tpgb + (size_t)t * (TAG * NBLK) : tpgb;
    const unsigned ep = 2u * (unsigned)t + 1u;

    // ---- phase A: e from prefetched U + VT[pred]; gates from sh=h_{t-1} ----
    {
      float ev = u_cur + VT[(size_t)pred * EMB + tid];
      se[tid] = ev > 0.0f ? ev : 0.0f;
    }
    __syncthreads();
    float acc0 = 0.0f, acc1 = 0.0f;
#pragma unroll
    for (int it = 0; it < 8; ++it) {   // e part: 1024 (weights from LDS)
      float4 w = sWiF4[rt * 256 + q + 32 * it], x = sef[q + 32 * it];
      acc0 += w.x * x.x + w.y * x.y + w.z * x.z + w.w * x.w;
    }
#pragma unroll
    for (int it = 0; it < 16; ++it) {  // h part: 2048 (weights from VGPRs)
      float4 w = rwh[it], x = shf[q + 32 * it];
      acc1 += w.x * x.x + w.y * x.y + w.z * x.z + w.w * x.w;
    }
    float acc = acc0 + acc1;
#pragma unroll
    for (int d = 16; d > 0; d >>= 1) acc += __shfl_down(acc, d, 32);
    if (q == 0) sg[rt] = acc + bsum;
    __syncthreads();
    if (tid < 8) {                      // wave 0: covered by gbar's vmcnt(0)
      float iv = sigf(sg[tid]);
      float fv = sigf(sg[8 + tid]);
      float gv = tanhf(sg[16 + tid]);
      float ov = sigf(sg[24 + tid]);
      float c = fv * sc[tid] + iv * gv;
      sc[tid] = c;
      astore(hrow + u0 + tid, ov * tanhf(c));
    }
    gbar(flags, ep);

    // ---- phase B: stage sh = h_t; prefetch U[t+1]; interm + tag partials ----
    if (FRESH) {
      if (tid < 512) ((float4*)sh)[tid] = ((const float4*)hrow)[tid];
    } else {
      sh[tid] = aload(hrow + tid);
      sh[tid + 1024] = aload(hrow + tid + 1024);
    }
    float u_nxt = (t + 1 < T_STEPS) ? U[(size_t)(t + 1) * EMB + tid] : 0.0f;
    __syncthreads();
    {
      float a2 = 0.0f;
      {
        float4 w = rwm[0], x = shf[bq];
        a2 += w.x * x.x + w.y * x.y + w.z * x.z + w.w * x.w;
        w = rwm[1]; x = shf[bq + 256];
        a2 += w.x * x.x + w.y * x.y + w.z * x.z + w.w * x.w;
      }
#pragma unroll
      for (int d = 32; d > 0; d >>= 1) a2 += __shfl_down(a2, d, 64);
      if ((tid & 63) == 0) wpart[tid >> 6] = a2;
      __syncthreads();
      if (tid < 4) {
        float v = wpart[tid * 4] + wpart[tid * 4 + 1] + wpart[tid * 4 + 2] +
                  wpart[tid * 4 + 3] + bitv;
        siv[tid] = v > 0.0f ? v : 0.0f;
      }
      __syncthreads();
      if (tid < TAG) {                  // wave 0: covered by gbar's vmcnt(0)
        float tpv = wt0 * siv[0] + wt1 * siv[1] + wt2 * siv[2] + wt3 * siv[3];
        astore(tpb + tid * NBLK + b, tpv);
      }
    }
    gbar(flags, ep + 1u);

    // ---- phase C: reduce tags; argmax everywhere; softmax only on block 0 ----
    {
      const int w = tid >> 6, l = tid & 63;  // 16 waves == 16 tags
      float v;
      if (FRESH) {
        const float4 p4 = ((const float4*)(tpb + w * NBLK))[l];
        v = p4.x + p4.y + p4.z + p4.w;
      } else {
        const float* p = tpb + w * NBLK + 4 * l;
        v = aload(p) + aload(p + 1) + aload(p + 2) + aload(p + 3);
      }
#pragma unroll
      for (int d = 32; d > 0; d >>= 1) v += __shfl_down(v, d, 64);
      if (l == 0) stv[w] = v + btw;
      __syncthreads();
      int am = 0;
      float bv = stv[0];
#pragma unroll
      for (int k = 1; k < TAG; ++k) {
        if (stv[k] > bv) { bv = stv[k]; am = k; }
      }
      pred = am;
      if (b == 0) {
        if (tid < TAG) {      // lanes 0-15 of wave 0: the only softmax computed
          float m = stv[0];
#pragma unroll
          for (int k = 1; k < TAG; ++k) m = fmaxf(m, stv[k]);
          float s = expf(stv[tid] - m);
#pragma unroll
          for (int msk = 8; msk > 0; msk >>= 1) s += __shfl_xor(s, msk, 16);
          float ls = logf(s);
          float lp = stv[tid] - m - ls;
          out[OUT_LOGP + t * TAG + tid] = lp;
          out[OUT_PROB + t * TAG + tid] = expf(lp);
        } else if (tid == TAG) {
          out[OUT_PRED + t] = (float)am;
        }
      }
      u_cur = u_nxt;
      __syncthreads();  // stv reads done before any next-iter LDS writes
    }
  }
}

extern "C" void kernel_launch(void* const* d_in, const int* in_sizes, int n_in,
                              void* d_out, int out_size, void* d_ws, size_t ws_size,
                              hipStream_t stream) {
  const float* seq = (const float*)d_in[0];
  const float* W_embed = (const float*)d_in[1];
  const float* b_embed = (const float*)d_in[2];
  const float* W_ih = (const float*)d_in[3];
  const float* W_hh = (const float*)d_in[4];
  const float* b_ih = (const float*)d_in[5];
  const float* b_hh = (const float*)d_in[6];
  const float* W_interm = (const float*)d_in[7];
  const float* b_interm = (const float*)d_in[8];
  const float* W_tag = (const float*)d_in[9];
  const float* b_tag = (const float*)d_in[10];
  (void)in_sizes; (void)n_in; (void)out_size;

  // ws layout: [flags 4K][VT 64K][hbuf][tpg][U 16M]
  const size_t flg_b = 4096;
  const size_t vt_b = (size_t)TAG * EMB * 4;
  const size_t u_b = (size_t)T_STEPS * EMB * 4;
  const size_t h_fresh = (size_t)T_STEPS * HID * 4;          // 32 MB
  const size_t tp_fresh = (size_t)T_STEPS * TAG * NBLK * 4;  // 64 MB
  const size_t h_small = (size_t)HID * 4;
  const size_t tp_small = (size_t)TAG * NBLK * 4;
  const int fresh = (ws_size >= flg_b + vt_b + u_b + h_fresh + tp_fresh) ? 1 : 0;
  const size_t h_b = fresh ? h_fresh : h_small;
  const size_t tp_b = fresh ? tp_fresh : tp_small;

  char* ws = (char*)d_ws;
  unsigned* flags = (unsigned*)ws;
  float* VT = (float*)(ws + flg_b);
  float* hbuf = (float*)(ws + flg_b + vt_b);
  float* tpg = (float*)(ws + flg_b + vt_b + h_b);
  float* U = (float*)(ws + flg_b + vt_b + h_b + tp_b);
  float* out = (float*)d_out;

  hipMemsetAsync(ws, 0, flg_b, stream);  // only flags need zeroing

  hipLaunchKernelGGL(rnnss_vt_kernel, dim3((TAG * EMB) / 256), dim3(256), 0, stream,
                     W_embed, VT);
  hipLaunchKernelGGL(rnnss_uprep, dim3(T_STEPS / 64, EMB / 64), dim3(256), 0, stream,
                     seq, W_embed, b_embed, U);

  void* args[] = {
      (void*)&W_ih,    (void*)&W_hh,  (void*)&b_ih,  (void*)&b_hh,
      (void*)&W_interm,(void*)&b_interm, (void*)&W_tag, (void*)&b_tag,
      (void*)&U,       (void*)&VT,    (void*)&hbuf,  (void*)&tpg,
      (void*)&flags,   (void*)&out};
  if (fresh) {
    hipLaunchCooperativeKernel((const void*)rnnss_persist<1>, dim3(NBLK), dim3(NTHR),
                               args, 0, stream);
  } else {
    hipLaunchCooperativeKernel((const void*)rnnss_persist<0>, dim3(NBLK), dim3(NTHR),
                               args, 0, stream);
  }
}

// Round 7
// 53816.553 us; speedup vs baseline: 1.0086x; 1.0086x over previous
//
#include <hip/hip_runtime.h>
#include <math.h>

#define T_STEPS 4096
#define EMB 1024
#define HID 2048
#define CAT 1040
#define TAG 16
#define NBLK 256
#define NTHR 1024

// 128B comm line per block (32 u32 words), 128B-strided (R5-proven: arrivals
// on distinct lines -> parallel at the coherent point; R6's packed flags
// serialized 64 stores/line and regressed 1.45x).
#define LWORDS 32
#define LN_EPA 0    // word 0 : epoch A (h ready)
#define LN_H   4    // words 4..11 : this block's 8 h values
#define LN_EPB 12   // word 12: epoch B (tag partials ready)
#define LN_TP  16   // words 16..31: this block's 16 tag partials

// output offsets (floats)
#define OUT_LOGP 0
#define OUT_PROB (T_STEPS * TAG)
#define OUT_PRED (2 * T_STEPS * TAG)

__device__ __forceinline__ float sigf(float x) { return 1.0f / (1.0f + expf(-x)); }

__device__ __forceinline__ unsigned aloadu(const unsigned* p) {
  return __hip_atomic_load(p, __ATOMIC_RELAXED, __HIP_MEMORY_SCOPE_AGENT);
}
__device__ __forceinline__ void astoreu(unsigned* p, unsigned v) {
  __hip_atomic_store(p, v, __ATOMIC_RELAXED, __HIP_MEMORY_SCOPE_AGENT);
}
__device__ __forceinline__ unsigned long long aload64(const unsigned long long* p) {
  return __hip_atomic_load(p, __ATOMIC_RELAXED, __HIP_MEMORY_SCOPE_AGENT);
}
__device__ __forceinline__ void astoref(float* p, float v) {
  __hip_atomic_store(p, v, __ATOMIC_RELAXED, __HIP_MEMORY_SCOPE_AGENT);
}

// ---- VT[p][i] = W_embed[i][1024+p]  (compact one-hot columns) ----
__global__ __launch_bounds__(256) void rnnss_vt_kernel(const float* __restrict__ We,
                                                       float* __restrict__ VT) {
  int n = blockIdx.x * 256 + threadIdx.x;      // 0..16383
  int p = n >> 10, i = n & 1023;
  VT[n] = We[(size_t)i * CAT + EMB + p];
}

// ---- U[t][i] = sum_k seq[t][k] * W_embed[i][k] + b_embed[i] ----
__global__ __launch_bounds__(256) void rnnss_uprep(const float* __restrict__ X,
                                                   const float* __restrict__ W,
                                                   const float* __restrict__ be,
                                                   float* __restrict__ U) {
  __shared__ __align__(16) float As[32][68];
  __shared__ __align__(16) float Bs[32][68];
  const int bm = blockIdx.x * 64;
  const int bn = blockIdx.y * 64;
  const int tid = threadIdx.x;
  const int tx = tid & 15, ty = tid >> 4;
  const int lr = tid >> 5, lc = tid & 31;
  float acc[4][4] = {};
  for (int k0 = 0; k0 < EMB; k0 += 32) {
#pragma unroll
    for (int p = 0; p < 8; ++p) {
      As[lc][lr + 8 * p] = X[(size_t)(bm + lr + 8 * p) * EMB + k0 + lc];
      Bs[lc][lr + 8 * p] = W[(size_t)(bn + lr + 8 * p) * CAT + k0 + lc];
    }
    __syncthreads();
#pragma unroll 8
    for (int k = 0; k < 32; ++k) {
      const float4 a = *(const float4*)&As[k][ty * 4];
      const float4 v = *(const float4*)&Bs[k][tx * 4];
      float am[4] = {a.x, a.y, a.z, a.w};
      float bv[4] = {v.x, v.y, v.z, v.w};
#pragma unroll
      for (int m = 0; m < 4; ++m)
#pragma unroll
        for (int n = 0; n < 4; ++n) acc[m][n] = fmaf(am[m], bv[n], acc[m][n]);
    }
    __syncthreads();
  }
#pragma unroll
  for (int m = 0; m < 4; ++m)
#pragma unroll
    for (int n = 0; n < 4; ++n)
      U[(size_t)(bm + ty * 4 + m) * EMB + bn + tx * 4 + n] =
          acc[m][n] + be[bn + tx * 4 + n];
}

// ---- persistent LSTM labeler: 256 blocks x 1024 threads ----
// Comm: each block owns ONE 128B line carrying {epochA, h[8], epochB, tp[16]}.
// Barrier poll and payload read are the SAME line -> one MALL round trip per
// sync instead of poll + separate bulk broadcast. All cross-block words are
// relaxed agent atomics; zero fences -> L2-resident weights/U/VT all run.
__global__ __launch_bounds__(NTHR, 4) void rnnss_persist(
    const float* __restrict__ Wih, const float* __restrict__ Whh,
    const float* __restrict__ bih, const float* __restrict__ bhh,
    const float* __restrict__ Witm, const float* __restrict__ bitm,
    const float* __restrict__ Wtag, const float* __restrict__ btag,
    const float* __restrict__ U, const float* __restrict__ VT,
    unsigned* __restrict__ lines,   // [256][32] u32, zeroed
    float* __restrict__ out) {
  __shared__ __align__(16) float sWi[32 * 1024];  // 128 KB: this block's W_ih rows
  __shared__ __align__(16) float se[EMB];
  __shared__ __align__(16) float sh[HID];
  __shared__ float sg[32];       // gate preacts for this block's 8 units
  __shared__ float wpart[16];    // per-wave partials (phase B)
  __shared__ float wsum[4][16];  // per-wave tag sums (phase C)
  __shared__ float stv[TAG];     // reduced tag scores
  __shared__ float sc[8];        // persistent cell state (block-owned units)

  const int tid = threadIdx.x;
  const int b = blockIdx.x;
  const int u0 = b * 8;                 // hidden units [u0, u0+8)
  unsigned* __restrict__ lnm = lines + (size_t)b * LWORDS;  // my line
  if (tid < 8) sc[tid] = 0.0f;
  sh[tid] = 0.0f;                       // h_0 = 0
  sh[tid + 1024] = 0.0f;

  // phase A row task: 32 gate rows x 32 lanes
  const int rt = tid >> 5;              // 0..31 : gsec*8 + j
  const int q = tid & 31;
  const int gsec = rt >> 3, j = rt & 7;
  const int grow = gsec * HID + u0 + j;
  const float bsum = bih[grow] + bhh[grow];
  const float4* __restrict__ wh = (const float4*)(Whh + (size_t)grow * HID);

  // phase B row task: 4 interm rows x 256 lanes
  const int brow = tid >> 8, bq = tid & 255;
  const float4* __restrict__ wm = (const float4*)(Witm + (size_t)(b * 4 + brow) * HID);
  float bi0 = 0, bi1 = 0, bi2 = 0, bi3 = 0;     // b_interm for this block's 4 rows
  float wt0 = 0, wt1 = 0, wt2 = 0, wt3 = 0;     // W_tag column slice for tag=tid
  float bt = 0.0f;
  if (tid < TAG) {
    bi0 = bitm[b * 4 + 0];
    bi1 = bitm[b * 4 + 1];
    bi2 = bitm[b * 4 + 2];
    bi3 = bitm[b * 4 + 3];
    wt0 = Wtag[(size_t)tid * 1024 + b * 4 + 0];
    wt1 = Wtag[(size_t)tid * 1024 + b * 4 + 1];
    wt2 = Wtag[(size_t)tid * 1024 + b * 4 + 2];
    wt3 = Wtag[(size_t)tid * 1024 + b * 4 + 3];
    bt = btag[tid];
  }

  // ---- prologue: W_ih slice -> LDS (coalesced float4) ----
  {
    const float4* WiF = (const float4*)Wih;
    float4* sWiF = (float4*)sWi;
#pragma unroll
    for (int n = 0; n < 8; ++n) {
      int idx = tid + 1024 * n;          // 0..8191 float4s
      int r = idx >> 8, c = idx & 255;
      int gr = (r >> 3) * HID + u0 + (r & 7);
      sWiF[idx] = WiF[(size_t)gr * 256 + c];
    }
  }

  // ---- prologue: W_hh + W_interm slices -> registers, PINNED ----
  float4 rwh[16], rwm[2];
#pragma unroll
  for (int it = 0; it < 16; ++it) rwh[it] = wh[q + 32 * it];
  rwm[0] = wm[bq];
  rwm[1] = wm[bq + 256];
#pragma unroll
  for (int it = 0; it < 16; ++it)
    asm volatile("" : "+v"(rwh[it].x), "+v"(rwh[it].y), "+v"(rwh[it].z), "+v"(rwh[it].w));
  asm volatile("" : "+v"(rwm[0].x), "+v"(rwm[0].y), "+v"(rwm[0].z), "+v"(rwm[0].w));
  asm volatile("" : "+v"(rwm[1].x), "+v"(rwm[1].y), "+v"(rwm[1].z), "+v"(rwm[1].w));

  const float4* sef = (const float4*)se;
  const float4* shf = (const float4*)sh;
  const float4* sWiF4 = (const float4*)sWi;

  int pred = 0;               // __START__
  float u_cur = U[tid];       // U[0] prefetched
  __syncthreads();            // sWi / sc / sh ready

  for (int t = 0; t < T_STEPS; ++t) {
    const unsigned ep = (unsigned)t + 1u;

    // ---- phase A: e from prefetched U + VT[pred]; gates from sh = h_{t-1} ----
    {
      float ev = u_cur + VT[(size_t)pred * EMB + tid];
      se[tid] = ev > 0.0f ? ev : 0.0f;
    }
    __syncthreads();                                  // (1) se ready
    float acc0 = 0.0f, acc1 = 0.0f;
#pragma unroll
    for (int it = 0; it < 8; ++it) {   // e part: 1024 (weights from LDS)
      float4 w = sWiF4[rt * 256 + q + 32 * it], x = sef[q + 32 * it];
      acc0 += w.x * x.x + w.y * x.y + w.z * x.z + w.w * x.w;
    }
#pragma unroll
    for (int it = 0; it < 16; ++it) {  // h part: 2048 (weights from VGPRs)
      float4 w = rwh[it], x = shf[q + 32 * it];
      acc1 += w.x * x.x + w.y * x.y + w.z * x.z + w.w * x.w;
    }
    float acc = acc0 + acc1;
#pragma unroll
    for (int d = 16; d > 0; d >>= 1) acc += __shfl_down(acc, d, 32);
    if (q == 0) sg[rt] = acc + bsum;
    __syncthreads();                                  // (2) sg ready; sh reads done
    if (tid < 8) {                      // wave 0
      float iv = sigf(sg[tid]);
      float fv = sigf(sg[8 + tid]);
      float gv = tanhf(sg[16 + tid]);
      float ov = sigf(sg[24 + tid]);
      float c = fv * sc[tid] + iv * gv;
      sc[tid] = c;
      astoref((float*)(lnm + LN_H) + tid, ov * tanhf(c));
    }
    if (tid == 0) {                     // wave 0: drain h stores, then flag
      asm volatile("s_waitcnt vmcnt(0)" ::: "memory");
      astoreu(lnm + LN_EPA, ep);
    }

    // ---- barrier 1 + fused h gather: poll line tid, read its 8 h words ----
    if (tid < NBLK) {
      const unsigned* ln = lines + (size_t)tid * LWORDS;
      while (aloadu(ln + LN_EPA) < ep) __builtin_amdgcn_s_sleep(1);
      asm volatile("" ::: "memory");
      const unsigned long long* hp = (const unsigned long long*)(ln + LN_H);
#pragma unroll
      for (int k = 0; k < 4; ++k) {
        unsigned long long v = aload64(hp + k);
        sh[tid * 8 + 2 * k] = __uint_as_float((unsigned)v);
        sh[tid * 8 + 2 * k + 1] = __uint_as_float((unsigned)(v >> 32));
      }
    }
    float u_nxt = (t + 1 < T_STEPS) ? U[(size_t)(t + 1) * EMB + tid] : 0.0f;
    __syncthreads();                                  // (3) sh = h_t ready

    // ---- phase B: interm partials + tag partials, all in regs/LDS ----
    {
      float a2 = 0.0f;
      float4 w = rwm[0], x = shf[bq];
      a2 += w.x * x.x + w.y * x.y + w.z * x.z + w.w * x.w;
      w = rwm[1]; x = shf[bq + 256];
      a2 += w.x * x.x + w.y * x.y + w.z * x.z + w.w * x.w;
#pragma unroll
      for (int d = 32; d > 0; d >>= 1) a2 += __shfl_down(a2, d, 64);
      if ((tid & 63) == 0) wpart[tid >> 6] = a2;
    }
    __syncthreads();                                  // (4) wpart ready
    if (tid < TAG) {                    // wave 0: finish interm rows + tag partial
      float i0 = wpart[0] + wpart[1] + wpart[2] + wpart[3] + bi0;
      float i1 = wpart[4] + wpart[5] + wpart[6] + wpart[7] + bi1;
      float i2 = wpart[8] + wpart[9] + wpart[10] + wpart[11] + bi2;
      float i3 = wpart[12] + wpart[13] + wpart[14] + wpart[15] + bi3;
      i0 = i0 > 0.0f ? i0 : 0.0f;
      i1 = i1 > 0.0f ? i1 : 0.0f;
      i2 = i2 > 0.0f ? i2 : 0.0f;
      i3 = i3 > 0.0f ? i3 : 0.0f;
      astoref((float*)(lnm + LN_TP) + tid, wt0 * i0 + wt1 * i1 + wt2 * i2 + wt3 * i3);
    }
    if (tid == 0) {                     // wave 0: drain tp stores, then flag
      asm volatile("s_waitcnt vmcnt(0)" ::: "memory");
      astoreu(lnm + LN_EPB, ep);
    }

    // ---- barrier 2 + fused tp gather + cross-thread tag reduce ----
    if (tid < NBLK) {
      const unsigned* ln = lines + (size_t)tid * LWORDS;
      while (aloadu(ln + LN_EPB) < ep) __builtin_amdgcn_s_sleep(1);
      asm volatile("" ::: "memory");
#pragma unroll
      for (int half = 0; half < 2; ++half) {
        const unsigned long long* tp8 =
            (const unsigned long long*)(ln + LN_TP + half * 8);
        float p[8];
#pragma unroll
        for (int k = 0; k < 4; ++k) {
          unsigned long long v = aload64(tp8 + k);
          p[2 * k] = __uint_as_float((unsigned)v);
          p[2 * k + 1] = __uint_as_float((unsigned)(v >> 32));
        }
#pragma unroll
        for (int k = 0; k < 8; ++k) {
#pragma unroll
          for (int d = 32; d > 0; d >>= 1) p[k] += __shfl_xor(p[k], d, 64);
        }
        if ((tid & 63) == 0) {
#pragma unroll
          for (int k = 0; k < 8; ++k) wsum[tid >> 6][half * 8 + k] = p[k];
        }
      }
    }
    __syncthreads();                                  // (5) wsum ready
    if (tid < TAG)
      stv[tid] = wsum[0][tid] + wsum[1][tid] + wsum[2][tid] + wsum[3][tid] + bt;
    __syncthreads();                                  // (6) stv ready

    // ---- phase C: argmax everywhere; softmax only on block 0 ----
    {
      int am = 0;
      float bv = stv[0];
#pragma unroll
      for (int k = 1; k < TAG; ++k) {
        if (stv[k] > bv) { bv = stv[k]; am = k; }
      }
      pred = am;
      if (b == 0) {
        if (tid < TAG) {
          float m = stv[0];
#pragma unroll
          for (int k = 1; k < TAG; ++k) m = fmaxf(m, stv[k]);
          float s = expf(stv[tid] - m);
#pragma unroll
          for (int msk = 8; msk > 0; msk >>= 1) s += __shfl_xor(s, msk, 16);
          float ls = logf(s);
          float lp = stv[tid] - m - ls;
          out[OUT_LOGP + t * TAG + tid] = lp;
          out[OUT_PROB + t * TAG + tid] = expf(lp);
        } else if (tid == TAG) {
          out[OUT_PRED + t] = (float)am;
        }
      }
      u_cur = u_nxt;
      // no trailing sync needed: next write to stv/wsum is behind syncs (1)-(5)
    }
  }
}

extern "C" void kernel_launch(void* const* d_in, const int* in_sizes, int n_in,
                              void* d_out, int out_size, void* d_ws, size_t ws_size,
                              hipStream_t stream) {
  const float* seq = (const float*)d_in[0];
  const float* W_embed = (const float*)d_in[1];
  const float* b_embed = (const float*)d_in[2];
  const float* W_ih = (const float*)d_in[3];
  const float* W_hh = (const float*)d_in[4];
  const float* b_ih = (const float*)d_in[5];
  const float* b_hh = (const float*)d_in[6];
  const float* W_interm = (const float*)d_in[7];
  const float* b_interm = (const float*)d_in[8];
  const float* W_tag = (const float*)d_in[9];
  const float* b_tag = (const float*)d_in[10];
  (void)in_sizes; (void)n_in; (void)out_size; (void)ws_size;

  // ws layout: [lines 32K][VT 64K][U 16M]
  const size_t ln_b = (size_t)NBLK * LWORDS * 4;
  const size_t vt_b = (size_t)TAG * EMB * 4;

  char* ws = (char*)d_ws;
  unsigned* lines = (unsigned*)ws;
  float* VT = (float*)(ws + ln_b);
  float* U = (float*)(ws + ln_b + vt_b);
  float* out = (float*)d_out;

  hipMemsetAsync(ws, 0, ln_b, stream);  // zero comm lines (epochs restart at 1)

  hipLaunchKernelGGL(rnnss_vt_kernel, dim3((TAG * EMB) / 256), dim3(256), 0, stream,
                     W_embed, VT);
  hipLaunchKernelGGL(rnnss_uprep, dim3(T_STEPS / 64, EMB / 64), dim3(256), 0, stream,
                     seq, W_embed, b_embed, U);

  void* args[] = {
      (void*)&W_ih,    (void*)&W_hh,  (void*)&b_ih,  (void*)&b_hh,
      (void*)&W_interm,(void*)&b_interm, (void*)&W_tag, (void*)&b_tag,
      (void*)&U,       (void*)&VT,    (void*)&lines, (void*)&out};
  hipLaunchCooperativeKernel((const void*)rnnss_persist, dim3(NBLK), dim3(NTHR),
                             args, 0, stream);
}

// Round 8
// 37191.348 us; speedup vs baseline: 1.4594x; 1.4470x over previous
//
#include <hip/hip_runtime.h>
#include <math.h>

#define T_STEPS 4096
#define EMB 1024
#define HID 2048
#define CAT 1040
#define TAG 16
#define NBLK 256
#define NTHR 1024
#define FLAG_STRIDE 32   // u32s per arrival-flag slot = 128B (own line; R5-proven)

// output offsets (floats)
#define OUT_LOGP 0
#define OUT_PROB (T_STEPS * TAG)
#define OUT_PRED (2 * T_STEPS * TAG)

__device__ __forceinline__ float sigf(float x) { return 1.0f / (1.0f + expf(-x)); }

__device__ __forceinline__ unsigned aloadu(const unsigned* p) {
  return __hip_atomic_load(p, __ATOMIC_RELAXED, __HIP_MEMORY_SCOPE_AGENT);
}
__device__ __forceinline__ void astoreu(unsigned* p, unsigned v) {
  __hip_atomic_store(p, v, __ATOMIC_RELAXED, __HIP_MEMORY_SCOPE_AGENT);
}
__device__ __forceinline__ float aloadf(const float* p) {
  return __hip_atomic_load(p, __ATOMIC_RELAXED, __HIP_MEMORY_SCOPE_AGENT);
}
__device__ __forceinline__ void astoref(float* p, float v) {
  __hip_atomic_store(p, v, __ATOMIC_RELAXED, __HIP_MEMORY_SCOPE_AGENT);
}

// ---- VT[p][i] = W_embed[i][1024+p]  (compact one-hot columns) ----
__global__ __launch_bounds__(256) void rnnss_vt_kernel(const float* __restrict__ We,
                                                       float* __restrict__ VT) {
  int n = blockIdx.x * 256 + threadIdx.x;      // 0..16383
  int p = n >> 10, i = n & 1023;
  VT[n] = We[(size_t)i * CAT + EMB + p];
}

// ---- U[t][i] = sum_k seq[t][k] * W_embed[i][k] + b_embed[i] ----
__global__ __launch_bounds__(256) void rnnss_uprep(const float* __restrict__ X,
                                                   const float* __restrict__ W,
                                                   const float* __restrict__ be,
                                                   float* __restrict__ U) {
  __shared__ __align__(16) float As[32][68];
  __shared__ __align__(16) float Bs[32][68];
  const int bm = blockIdx.x * 64;
  const int bn = blockIdx.y * 64;
  const int tid = threadIdx.x;
  const int tx = tid & 15, ty = tid >> 4;
  const int lr = tid >> 5, lc = tid & 31;
  float acc[4][4] = {};
  for (int k0 = 0; k0 < EMB; k0 += 32) {
#pragma unroll
    for (int p = 0; p < 8; ++p) {
      As[lc][lr + 8 * p] = X[(size_t)(bm + lr + 8 * p) * EMB + k0 + lc];
      Bs[lc][lr + 8 * p] = W[(size_t)(bn + lr + 8 * p) * CAT + k0 + lc];
    }
    __syncthreads();
#pragma unroll 8
    for (int k = 0; k < 32; ++k) {
      const float4 a = *(const float4*)&As[k][ty * 4];
      const float4 v = *(const float4*)&Bs[k][tx * 4];
      float am[4] = {a.x, a.y, a.z, a.w};
      float bv[4] = {v.x, v.y, v.z, v.w};
#pragma unroll
      for (int m = 0; m < 4; ++m)
#pragma unroll
        for (int n = 0; n < 4; ++n) acc[m][n] = fmaf(am[m], bv[n], acc[m][n]);
    }
    __syncthreads();
  }
#pragma unroll
  for (int m = 0; m < 4; ++m)
#pragma unroll
    for (int n = 0; n < 4; ++n)
      U[(size_t)(bm + ty * 4 + m) * EMB + bn + tx * 4 + n] =
          acc[m][n] + be[bn + tx * 4 + n];
}

// ---- persistent LSTM labeler: 256 blocks x 1024 threads ----
// Comm fabric (R5-proven + one change):
//  - flags: 128B-strided arrival lines, relaxed agent atomics, fence-free.
//  - h: t-indexed FRESH rows. Producers astore 8 words (-> MALL, drained
//    before flag); consumers use PLAIN coalesced float4 loads: fresh lines
//    cannot be stale in any cache, so XCD-L2 MSHRs merge the 32 blocks/XCD
//    into ~64 MALL fetches (correctness of this exact path validated in R6).
//  - tpg: reused lines -> stays fully atomic; stores 1KB-strided (parallel),
//    reads wave-coalesced contiguous (R5-proven).
__global__ __launch_bounds__(NTHR, 4) void rnnss_persist(
    const float* __restrict__ Wih, const float* __restrict__ Whh,
    const float* __restrict__ bih, const float* __restrict__ bhh,
    const float* __restrict__ Witm, const float* __restrict__ bitm,
    const float* __restrict__ Wtag, const float* __restrict__ btag,
    const float* __restrict__ U, const float* __restrict__ VT,
    float* __restrict__ hbase,  // [T][2048] fresh rows
    float* __restrict__ tpg,    // [16][256]
    unsigned* __restrict__ flags,
    float* __restrict__ out) {
  __shared__ __align__(16) float sWi[32 * 1024];  // 128 KB: this block's W_ih rows
  __shared__ __align__(16) float se[EMB];
  __shared__ __align__(16) float sh[HID];
  __shared__ float sg[32];     // gate preacts for this block's 8 units
  __shared__ float wpart[16];  // per-wave partials (phase B)
  __shared__ float stv[TAG];   // reduced tag scores
  __shared__ float sc[8];      // persistent cell state (block-owned units)

  const int tid = threadIdx.x;
  const int b = blockIdx.x;
  const int u0 = b * 8;                 // hidden units [u0, u0+8)
  if (tid < 8) sc[tid] = 0.0f;
  sh[tid] = 0.0f;                       // h_0 = 0 (phase A reads sh, never global)
  sh[tid + 1024] = 0.0f;

  // phase A row task: 32 gate rows x 32 lanes
  const int rt = tid >> 5;              // 0..31 : gsec*8 + j
  const int q = tid & 31;
  const int gsec = rt >> 3, j = rt & 7;
  const int grow = gsec * HID + u0 + j;
  const float bsum = bih[grow] + bhh[grow];
  const float4* __restrict__ wh = (const float4*)(Whh + (size_t)grow * HID);

  // phase B row task: 4 interm rows x 256 lanes
  const int brow = tid >> 8, bq = tid & 255;
  const float4* __restrict__ wm = (const float4*)(Witm + (size_t)(b * 4 + brow) * HID);
  float bi0 = 0, bi1 = 0, bi2 = 0, bi3 = 0;
  float wt0 = 0, wt1 = 0, wt2 = 0, wt3 = 0;
  if (tid < TAG) {
    bi0 = bitm[b * 4 + 0];
    bi1 = bitm[b * 4 + 1];
    bi2 = bitm[b * 4 + 2];
    bi3 = bitm[b * 4 + 3];
    wt0 = Wtag[(size_t)tid * 1024 + b * 4 + 0];
    wt1 = Wtag[(size_t)tid * 1024 + b * 4 + 1];
    wt2 = Wtag[(size_t)tid * 1024 + b * 4 + 2];
    wt3 = Wtag[(size_t)tid * 1024 + b * 4 + 3];
  }
  float btw = 0.0f;
  if ((tid & 63) == 0) btw = btag[tid >> 6];

  // ---- prologue: W_ih slice -> LDS (coalesced float4) ----
  {
    const float4* WiF = (const float4*)Wih;
    float4* sWiF = (float4*)sWi;
#pragma unroll
    for (int n = 0; n < 8; ++n) {
      int idx = tid + 1024 * n;          // 0..8191 float4s
      int r = idx >> 8, c = idx & 255;
      int gr = (r >> 3) * HID + u0 + (r & 7);
      sWiF[idx] = WiF[(size_t)gr * 256 + c];
    }
  }

  // ---- prologue: W_hh + W_interm slices -> registers, PINNED ----
  float4 rwh[16], rwm[2];
#pragma unroll
  for (int it = 0; it < 16; ++it) rwh[it] = wh[q + 32 * it];
  rwm[0] = wm[bq];
  rwm[1] = wm[bq + 256];
#pragma unroll
  for (int it = 0; it < 16; ++it)
    asm volatile("" : "+v"(rwh[it].x), "+v"(rwh[it].y), "+v"(rwh[it].z), "+v"(rwh[it].w));
  asm volatile("" : "+v"(rwm[0].x), "+v"(rwm[0].y), "+v"(rwm[0].z), "+v"(rwm[0].w));
  asm volatile("" : "+v"(rwm[1].x), "+v"(rwm[1].y), "+v"(rwm[1].z), "+v"(rwm[1].w));

  const float4* sef = (const float4*)se;
  const float4* shf = (const float4*)sh;
  const float4* sWiF4 = (const float4*)sWi;

  int pred = 0;               // __START__
  float u_cur = U[tid];       // U[0] prefetched
  __syncthreads();            // sWi / sc / sh ready

  for (int t = 0; t < T_STEPS; ++t) {
    float* __restrict__ hrow = hbase + (size_t)t * HID;
    const unsigned epA = 2u * (unsigned)t + 1u;

    // ---- phase A: e from prefetched U + VT[pred]; gates from sh = h_{t-1} ----
    {
      float ev = u_cur + VT[(size_t)pred * EMB + tid];
      se[tid] = ev > 0.0f ? ev : 0.0f;
    }
    __syncthreads();                                  // (1) se ready
    float acc0 = 0.0f, acc1 = 0.0f;
#pragma unroll
    for (int it = 0; it < 8; ++it) {   // e part: 1024 (weights from LDS)
      float4 w = sWiF4[rt * 256 + q + 32 * it], x = sef[q + 32 * it];
      acc0 += w.x * x.x + w.y * x.y + w.z * x.z + w.w * x.w;
    }
#pragma unroll
    for (int it = 0; it < 16; ++it) {  // h part: 2048 (weights from VGPRs)
      float4 w = rwh[it], x = shf[q + 32 * it];
      acc1 += w.x * x.x + w.y * x.y + w.z * x.z + w.w * x.w;
    }
    float acc = acc0 + acc1;
#pragma unroll
    for (int d = 16; d > 0; d >>= 1) acc += __shfl_down(acc, d, 32);
    if (q == 0) sg[rt] = acc + bsum;
    __syncthreads();                                  // (2) sg ready; sh reads done
    if (tid < 8) {                      // wave 0: LSTM pointwise + h out
      float iv = sigf(sg[tid]);
      float fv = sigf(sg[8 + tid]);
      float gv = tanhf(sg[16 + tid]);
      float ov = sigf(sg[24 + tid]);
      float c = fv * sc[tid] + iv * gv;
      sc[tid] = c;
      astoref(hrow + u0 + tid, ov * tanhf(c));
    }
    if (tid == 0) {                     // wave 0: drain h stores, then flag
      asm volatile("s_waitcnt vmcnt(0)" ::: "memory");
      astoreu(flags + (size_t)b * FLAG_STRIDE, epA);
    }
    if (tid < NBLK) {                   // barrier A: poll distinct lines
      const unsigned* f = flags + (size_t)tid * FLAG_STRIDE;
      while (aloadu(f) < epA) __builtin_amdgcn_s_sleep(1);
    }
    asm volatile("" ::: "memory");
    __syncthreads();                    // barrier A exit

    // ---- gather h_t: plain coalesced float4 (fresh lines, L2-merged) ----
    if (tid < 512) ((float4*)sh)[tid] = ((const float4*)hrow)[tid];
    float u_nxt = (t + 1 < T_STEPS) ? U[(size_t)(t + 1) * EMB + tid] : 0.0f;
    __syncthreads();                                  // (3) sh = h_t ready

    // ---- phase B: interm partials + tag partials ----
    {
      float a2 = 0.0f;
      float4 w = rwm[0], x = shf[bq];
      a2 += w.x * x.x + w.y * x.y + w.z * x.z + w.w * x.w;
      w = rwm[1]; x = shf[bq + 256];
      a2 += w.x * x.x + w.y * x.y + w.z * x.z + w.w * x.w;
#pragma unroll
      for (int d = 32; d > 0; d >>= 1) a2 += __shfl_down(a2, d, 64);
      if ((tid & 63) == 0) wpart[tid >> 6] = a2;
    }
    __syncthreads();                                  // (4) wpart ready
    if (tid < TAG) {                    // wave 0: finish interm + tag partial
      float i0 = wpart[0] + wpart[1] + wpart[2] + wpart[3] + bi0;
      float i1 = wpart[4] + wpart[5] + wpart[6] + wpart[7] + bi1;
      float i2 = wpart[8] + wpart[9] + wpart[10] + wpart[11] + bi2;
      float i3 = wpart[12] + wpart[13] + wpart[14] + wpart[15] + bi3;
      i0 = i0 > 0.0f ? i0 : 0.0f;
      i1 = i1 > 0.0f ? i1 : 0.0f;
      i2 = i2 > 0.0f ? i2 : 0.0f;
      i3 = i3 > 0.0f ? i3 : 0.0f;
      // 16 lanes -> 16 DIFFERENT lines (1KB stride): parallel at MALL
      astoref(tpg + tid * NBLK + b, wt0 * i0 + wt1 * i1 + wt2 * i2 + wt3 * i3);
    }
    if (tid == 0) {                     // wave 0: drain tp stores, then flag
      asm volatile("s_waitcnt vmcnt(0)" ::: "memory");
      astoreu(flags + (size_t)b * FLAG_STRIDE, epA + 1u);
    }
    if (tid < NBLK) {                   // barrier B
      const unsigned* f = flags + (size_t)tid * FLAG_STRIDE;
      while (aloadu(f) < epA + 1u) __builtin_amdgcn_s_sleep(1);
    }
    asm volatile("" ::: "memory");
    __syncthreads();                    // barrier B exit

    // ---- phase C: coalesced atomic tpg gather + reduce (R5-proven) ----
    {
      const int w = tid >> 6, l = tid & 63;  // 16 waves == 16 tags
      float v = aloadf(tpg + w * NBLK + l) + aloadf(tpg + w * NBLK + 64 + l) +
                aloadf(tpg + w * NBLK + 128 + l) + aloadf(tpg + w * NBLK + 192 + l);
#pragma unroll
      for (int d = 32; d > 0; d >>= 1) v += __shfl_down(v, d, 64);
      if (l == 0) stv[w] = v + btw;
    }
    __syncthreads();                                  // (5) stv ready
    {
      int am = 0;
      float bv = stv[0];
#pragma unroll
      for (int k = 1; k < TAG; ++k) {
        if (stv[k] > bv) { bv = stv[k]; am = k; }
      }
      pred = am;
      if (b == 0) {
        if (tid < TAG) {      // lanes 0-15 of wave 0: the only softmax computed
          float m = stv[0];
#pragma unroll
          for (int k = 1; k < TAG; ++k) m = fmaxf(m, stv[k]);
          float s = expf(stv[tid] - m);
#pragma unroll
          for (int msk = 8; msk > 0; msk >>= 1) s += __shfl_xor(s, msk, 16);
          float ls = logf(s);
          float lp = stv[tid] - m - ls;
          out[OUT_LOGP + t * TAG + tid] = lp;
          out[OUT_PROB + t * TAG + tid] = expf(lp);
        } else if (tid == TAG) {
          out[OUT_PRED + t] = (float)am;
        }
      }
      u_cur = u_nxt;
      // no trailing sync: stv/wpart/se next written behind >=1 sync of t+1
    }
  }
}

extern "C" void kernel_launch(void* const* d_in, const int* in_sizes, int n_in,
                              void* d_out, int out_size, void* d_ws, size_t ws_size,
                              hipStream_t stream) {
  const float* seq = (const float*)d_in[0];
  const float* W_embed = (const float*)d_in[1];
  const float* b_embed = (const float*)d_in[2];
  const float* W_ih = (const float*)d_in[3];
  const float* W_hh = (const float*)d_in[4];
  const float* b_ih = (const float*)d_in[5];
  const float* b_hh = (const float*)d_in[6];
  const float* W_interm = (const float*)d_in[7];
  const float* b_interm = (const float*)d_in[8];
  const float* W_tag = (const float*)d_in[9];
  const float* b_tag = (const float*)d_in[10];
  (void)in_sizes; (void)n_in; (void)out_size; (void)ws_size;

  // ws layout: [flags 32K][tpg 16K][VT 64K][hbase 32M][U 16M]
  const size_t flg_b = (size_t)NBLK * FLAG_STRIDE * 4;
  const size_t tp_b = (size_t)TAG * NBLK * 4;
  const size_t vt_b = (size_t)TAG * EMB * 4;
  const size_t h_b = (size_t)T_STEPS * HID * 4;

  char* ws = (char*)d_ws;
  unsigned* flags = (unsigned*)ws;
  float* tpg = (float*)(ws + flg_b);
  float* VT = (float*)(ws + flg_b + tp_b);
  float* hbase = (float*)(ws + flg_b + tp_b + vt_b);
  float* U = (float*)(ws + flg_b + tp_b + vt_b + h_b);
  float* out = (float*)d_out;

  hipMemsetAsync(ws, 0, flg_b, stream);  // only flags need zeroing

  hipLaunchKernelGGL(rnnss_vt_kernel, dim3((TAG * EMB) / 256), dim3(256), 0, stream,
                     W_embed, VT);
  hipLaunchKernelGGL(rnnss_uprep, dim3(T_STEPS / 64, EMB / 64), dim3(256), 0, stream,
                     seq, W_embed, b_embed, U);

  void* args[] = {
      (void*)&W_ih,    (void*)&W_hh,  (void*)&b_ih,  (void*)&b_hh,
      (void*)&W_interm,(void*)&b_interm, (void*)&W_tag, (void*)&b_tag,
      (void*)&U,       (void*)&VT,    (void*)&hbase, (void*)&tpg,
      (void*)&flags,   (void*)&out};
  hipLaunchCooperativeKernel((const void*)rnnss_persist, dim3(NBLK), dim3(NTHR),
                             args, 0, stream);
}